// Round 3
// baseline (564.413 us; speedup 1.0000x reference)
//
#include <hip/hip_runtime.h>

#define NDIN 128
#define NDOUT 64

// ---------------------------------------------------------------------------
// Kernel 1: xw = x @ W   (f32 vector GEMM; K=128, N=64)
// block = 256 = 4 waves; block handles 16 rows. W [128][64] (32KB) and the
// x tile [16][128] (8KB) both staged in LDS via coalesced loads. Inner loop
// reads are LDS broadcasts (free) / 2-way aliased (free).
// ---------------------------------------------------------------------------
__global__ __launch_bounds__(256) void gemm_xw_kernel(
    const float* __restrict__ x, const float* __restrict__ w,
    float* __restrict__ xw, int n_nodes) {
  __shared__ float wlds[NDIN][NDOUT];   // 32 KB
  __shared__ float xlds[16][NDIN];      // 8 KB
  const int t = threadIdx.x;

  const float4* w4 = (const float4*)w;
  float4* wl4 = (float4*)(&wlds[0][0]);
#pragma unroll
  for (int i = 0; i < (NDIN * NDOUT / 4) / 256; ++i)
    wl4[t + i * 256] = w4[t + i * 256];

  const int row_base = blockIdx.x * 16;
  float4* xl4 = (float4*)(&xlds[0][0]);
  const float4* x4 = (const float4*)(x + (size_t)row_base * NDIN);
  if (row_base + 16 <= n_nodes) {
    xl4[t] = x4[t];
    xl4[t + 256] = x4[t + 256];
  } else {
    for (int i = t; i < 16 * NDIN / 4; i += 256) {
      int row = row_base + i / (NDIN / 4);
      xl4[i] = (row < n_nodes) ? x4[i] : make_float4(0.f, 0.f, 0.f, 0.f);
    }
  }
  __syncthreads();

  const int col = t & 63;
  const int r = t >> 6;  // wave id: rows r*4 .. r*4+3 of the tile
  float acc[4] = {0.f, 0.f, 0.f, 0.f};
#pragma unroll
  for (int k = 0; k < NDIN; k += 4) {
    const float w0 = wlds[k][col], w1 = wlds[k + 1][col];
    const float w2 = wlds[k + 2][col], w3 = wlds[k + 3][col];
#pragma unroll
    for (int j = 0; j < 4; ++j) {
      float4 a = *(const float4*)(&xlds[r * 4 + j][k]);
      acc[j] += a.x * w0 + a.y * w1 + a.z * w2 + a.w * w3;
    }
  }
#pragma unroll
  for (int j = 0; j < 4; ++j) {
    const int row = row_base + r * 4 + j;
    if (row < n_nodes) xw[(size_t)row * NDOUT + col] = acc[j];
  }
}

// ---------------------------------------------------------------------------
// Kernel 2: per edge e: out[src[e], :] += edge_weight[e] * xw[dst[e], :]
// one wave per edge, lane = column. 4 edges unrolled per iteration so 4
// independent gathers are in flight; native fire-and-forget f32 atomics
// (unsafeAtomicAdd -> global_atomic_add_f32, no CAS loop, no return dep).
// ---------------------------------------------------------------------------
__global__ __launch_bounds__(256) void edge_scatter_kernel(
    const float* __restrict__ xw, const float* __restrict__ ew,
    const int* __restrict__ src, const int* __restrict__ dst,
    float* __restrict__ out, int n_edges) {
  const int lane = threadIdx.x & 63;
  const int wid = (blockIdx.x * 256 + threadIdx.x) >> 6;
  const int nw = (gridDim.x * 256) >> 6;

  for (int e0 = wid * 4; e0 < n_edges; e0 += nw * 4) {
    int s[4];
    float v[4];
    bool ok[4];
#pragma unroll
    for (int j = 0; j < 4; ++j) {
      const int e = e0 + j;
      ok[j] = (e < n_edges);
      const int ee = ok[j] ? e : 0;
      s[j] = src[ee];
      const int d = dst[ee];
      const float w = ew[ee];
      v[j] = xw[(size_t)d * NDOUT + lane] * w;
    }
#pragma unroll
    for (int j = 0; j < 4; ++j) {
      if (ok[j]) unsafeAtomicAdd(out + (size_t)s[j] * NDOUT + lane, v[j]);
    }
  }
}

// ---------------------------------------------------------------------------
// Kernel 3: in-place ReLU on out (float4-vectorized)
// ---------------------------------------------------------------------------
__global__ __launch_bounds__(256) void relu_kernel(float* __restrict__ out,
                                                   int n4) {
  float4* o4 = (float4*)out;
  int i = blockIdx.x * 256 + threadIdx.x;
  const int stride = gridDim.x * 256;
  for (; i < n4; i += stride) {
    float4 v = o4[i];
    v.x = fmaxf(v.x, 0.f);
    v.y = fmaxf(v.y, 0.f);
    v.z = fmaxf(v.z, 0.f);
    v.w = fmaxf(v.w, 0.f);
    o4[i] = v;
  }
}

extern "C" void kernel_launch(void* const* d_in, const int* in_sizes, int n_in,
                              void* d_out, int out_size, void* d_ws,
                              size_t ws_size, hipStream_t stream) {
  const float* x = (const float*)d_in[0];     // [N, 128]
  const float* ew = (const float*)d_in[1];    // [E]
  const float* w = (const float*)d_in[2];     // [128, 64]
  const int* esrc = (const int*)d_in[3];      // [E]
  const int* edst = (const int*)d_in[4];      // [E]
  float* out = (float*)d_out;                 // [N, 64]
  float* xw = (float*)d_ws;                   // [N, 64] scratch

  const int n_nodes = in_sizes[0] / NDIN;
  const int n_edges = in_sizes[1];

  // 1) xw = x @ W
  const int gblocks = (n_nodes + 15) / 16;
  gemm_xw_kernel<<<gblocks, 256, 0, stream>>>(x, w, xw, n_nodes);

  // 2) zero the output accumulator (harness poisons d_out with 0xAA)
  hipMemsetAsync(d_out, 0, (size_t)out_size * sizeof(float), stream);

  // 3) scatter-add messages (native f32 atomics)
  edge_scatter_kernel<<<2048, 256, 0, stream>>>(xw, ew, esrc, edst, out,
                                                n_edges);

  // 4) ReLU
  relu_kernel<<<1024, 256, 0, stream>>>(out, out_size / 4);
}

// Round 4
// 485.034 us; speedup vs baseline: 1.1637x; 1.1637x over previous
//
#include <hip/hip_runtime.h>

#define NDIN 128
#define NDOUT 64

// ---------------------------------------------------------------------------
// Kernel 1: xw = x @ W   (f32 vector GEMM; K=128, N=64)
// block = 256 = 4 waves; block handles 16 rows. W [128][64] (32KB) and the
// x tile [16][128] (8KB) staged in LDS via coalesced loads.
// ---------------------------------------------------------------------------
__global__ __launch_bounds__(256) void gemm_xw_kernel(
    const float* __restrict__ x, const float* __restrict__ w,
    float* __restrict__ xw, int n_nodes) {
  __shared__ float wlds[NDIN][NDOUT];   // 32 KB
  __shared__ float xlds[16][NDIN];      // 8 KB
  const int t = threadIdx.x;

  const float4* w4 = (const float4*)w;
  float4* wl4 = (float4*)(&wlds[0][0]);
#pragma unroll
  for (int i = 0; i < (NDIN * NDOUT / 4) / 256; ++i)
    wl4[t + i * 256] = w4[t + i * 256];

  const int row_base = blockIdx.x * 16;
  float4* xl4 = (float4*)(&xlds[0][0]);
  const float4* x4 = (const float4*)(x + (size_t)row_base * NDIN);
  if (row_base + 16 <= n_nodes) {
    xl4[t] = x4[t];
    xl4[t + 256] = x4[t + 256];
  } else {
    for (int i = t; i < 16 * NDIN / 4; i += 256) {
      int row = row_base + i / (NDIN / 4);
      xl4[i] = (row < n_nodes) ? x4[i] : make_float4(0.f, 0.f, 0.f, 0.f);
    }
  }
  __syncthreads();

  const int col = t & 63;
  const int r = t >> 6;
  float acc[4] = {0.f, 0.f, 0.f, 0.f};
#pragma unroll
  for (int k = 0; k < NDIN; k += 4) {
    const float w0 = wlds[k][col], w1 = wlds[k + 1][col];
    const float w2 = wlds[k + 2][col], w3 = wlds[k + 3][col];
#pragma unroll
    for (int j = 0; j < 4; ++j) {
      float4 a = *(const float4*)(&xlds[r * 4 + j][k]);
      acc[j] += a.x * w0 + a.y * w1 + a.z * w2 + a.w * w3;
    }
  }
#pragma unroll
  for (int j = 0; j < 4; ++j) {
    const int row = row_base + r * 4 + j;
    if (row < n_nodes) xw[(size_t)row * NDOUT + col] = acc[j];
  }
}

// ---------------------------------------------------------------------------
// CSR build: histogram -> exclusive scan (3 kernels) -> placement
// ---------------------------------------------------------------------------
__global__ __launch_bounds__(256) void hist_kernel(const int* __restrict__ src,
                                                   int* __restrict__ deg,
                                                   int n_edges) {
  int e = blockIdx.x * 256 + threadIdx.x;
  if (e < n_edges) atomicAdd(&deg[src[e]], 1);
}

__global__ __launch_bounds__(1024) void scan_block_kernel(
    const int* __restrict__ deg, int* __restrict__ row,
    int* __restrict__ bsums, int n) {
  __shared__ int s[1024];
  const int t = threadIdx.x;
  const int i = blockIdx.x * 1024 + t;
  const int v = (i < n) ? deg[i] : 0;
  s[t] = v;
  __syncthreads();
#pragma unroll
  for (int off = 1; off < 1024; off <<= 1) {
    int add = (t >= off) ? s[t - off] : 0;
    __syncthreads();
    s[t] += add;
    __syncthreads();
  }
  if (i < n) row[i] = s[t] - v;  // exclusive
  if (t == 1023) bsums[blockIdx.x] = s[1023];
}

__global__ __launch_bounds__(1024) void scan_tops_kernel(int* __restrict__ bsums,
                                                         int nb) {
  __shared__ int s[1024];
  const int t = threadIdx.x;
  const int v = (t < nb) ? bsums[t] : 0;
  s[t] = v;
  __syncthreads();
#pragma unroll
  for (int off = 1; off < 1024; off <<= 1) {
    int add = (t >= off) ? s[t - off] : 0;
    __syncthreads();
    s[t] += add;
    __syncthreads();
  }
  if (t < nb) bsums[t] = s[t] - v;  // exclusive over block sums
}

__global__ __launch_bounds__(256) void add_off_kernel(
    int* __restrict__ row, int* __restrict__ cursor,
    const int* __restrict__ bsums, int n, int n_edges) {
  const int i = blockIdx.x * 256 + threadIdx.x;
  if (i < n) {
    const int r = row[i] + bsums[i >> 10];
    row[i] = r;
    cursor[i] = r;
  }
  if (i == 0) row[n] = n_edges;
}

__global__ __launch_bounds__(256) void placement_kernel(
    const int* __restrict__ src, const int* __restrict__ dst,
    const float* __restrict__ ew, int* __restrict__ cursor,
    int2* __restrict__ bins, int n_edges) {
  const int e = blockIdx.x * 256 + threadIdx.x;
  if (e >= n_edges) return;
  const int s = src[e];
  const int p = atomicAdd(&cursor[s], 1);
  int2 b;
  b.x = dst[e];
  b.y = __float_as_int(ew[e]);
  bins[p] = b;
}

// ---------------------------------------------------------------------------
// Aggregate: one wave per node, lane = column. No float atomics; one
// coalesced store per node; ReLU fused.
// ---------------------------------------------------------------------------
__global__ __launch_bounds__(256) void aggregate_kernel(
    const float* __restrict__ xw, const int2* __restrict__ bins,
    const int* __restrict__ row, float* __restrict__ out, int n_nodes) {
  const int lane = threadIdx.x & 63;
  const int wid = (blockIdx.x * 256 + threadIdx.x) >> 6;
  const int nw = (gridDim.x * 256) >> 6;
  for (int n = wid; n < n_nodes; n += nw) {
    const int s0 = row[n], s1 = row[n + 1];
    float acc = 0.f;
    int i = s0;
    for (; i + 4 <= s1; i += 4) {
      const int2 b0 = bins[i], b1 = bins[i + 1];
      const int2 b2 = bins[i + 2], b3 = bins[i + 3];
      const float v0 = xw[(size_t)b0.x * NDOUT + lane];
      const float v1 = xw[(size_t)b1.x * NDOUT + lane];
      const float v2 = xw[(size_t)b2.x * NDOUT + lane];
      const float v3 = xw[(size_t)b3.x * NDOUT + lane];
      acc += __int_as_float(b0.y) * v0 + __int_as_float(b1.y) * v1 +
             __int_as_float(b2.y) * v2 + __int_as_float(b3.y) * v3;
    }
    for (; i < s1; ++i) {
      const int2 b = bins[i];
      acc += __int_as_float(b.y) * xw[(size_t)b.x * NDOUT + lane];
    }
    out[(size_t)n * NDOUT + lane] = fmaxf(acc, 0.f);
  }
}

// ---------------------------------------------------------------------------
// Fallback path (ws too small): atomic scatter + relu  (round-3 kernels)
// ---------------------------------------------------------------------------
__global__ __launch_bounds__(256) void edge_scatter_kernel(
    const float* __restrict__ xw, const float* __restrict__ ew,
    const int* __restrict__ src, const int* __restrict__ dst,
    float* __restrict__ out, int n_edges) {
  const int lane = threadIdx.x & 63;
  const int wid = (blockIdx.x * 256 + threadIdx.x) >> 6;
  const int nw = (gridDim.x * 256) >> 6;
  for (int e0 = wid * 4; e0 < n_edges; e0 += nw * 4) {
    int s[4];
    float v[4];
    bool ok[4];
#pragma unroll
    for (int j = 0; j < 4; ++j) {
      const int e = e0 + j;
      ok[j] = (e < n_edges);
      const int ee = ok[j] ? e : 0;
      s[j] = src[ee];
      const int d = dst[ee];
      v[j] = xw[(size_t)d * NDOUT + lane] * ew[ee];
    }
#pragma unroll
    for (int j = 0; j < 4; ++j) {
      if (ok[j]) unsafeAtomicAdd(out + (size_t)s[j] * NDOUT + lane, v[j]);
    }
  }
}

__global__ __launch_bounds__(256) void relu_kernel(float* __restrict__ out,
                                                   int n4) {
  float4* o4 = (float4*)out;
  int i = blockIdx.x * 256 + threadIdx.x;
  const int stride = gridDim.x * 256;
  for (; i < n4; i += stride) {
    float4 v = o4[i];
    v.x = fmaxf(v.x, 0.f);
    v.y = fmaxf(v.y, 0.f);
    v.z = fmaxf(v.z, 0.f);
    v.w = fmaxf(v.w, 0.f);
    o4[i] = v;
  }
}

extern "C" void kernel_launch(void* const* d_in, const int* in_sizes, int n_in,
                              void* d_out, int out_size, void* d_ws,
                              size_t ws_size, hipStream_t stream) {
  const float* x = (const float*)d_in[0];     // [N, 128]
  const float* ew = (const float*)d_in[1];    // [E]
  const float* w = (const float*)d_in[2];     // [128, 64]
  const int* esrc = (const int*)d_in[3];      // [E]
  const int* edst = (const int*)d_in[4];      // [E]
  float* out = (float*)d_out;                 // [N, 64]

  const int n_nodes = in_sizes[0] / NDIN;
  const int n_edges = in_sizes[1];

  // ws layout (CSR path):
  //   xw:     N*64 f32
  //   bins:   E int2
  //   row:    (N+1) int
  //   deg:    N int
  //   cursor: N int
  //   bsums:  1024 int
  char* base = (char*)d_ws;
  size_t off = 0;
  float* xw = (float*)(base + off); off += (size_t)n_nodes * NDOUT * 4;
  int2* bins = (int2*)(base + off); off += (size_t)n_edges * 8;
  int* rowp = (int*)(base + off); off += (size_t)(n_nodes + 1) * 4;
  int* deg = (int*)(base + off); off += (size_t)n_nodes * 4;
  int* cursor = (int*)(base + off); off += (size_t)n_nodes * 4;
  int* bsums = (int*)(base + off); off += 4096;
  const bool csr_ok = (ws_size >= off);

  // 1) xw = x @ W
  const int gblocks = (n_nodes + 15) / 16;
  gemm_xw_kernel<<<gblocks, 256, 0, stream>>>(x, w, xw, n_nodes);

  const int eblocks = (n_edges + 255) / 256;
  if (csr_ok) {
    // 2) CSR build
    hipMemsetAsync(deg, 0, (size_t)n_nodes * 4, stream);
    hist_kernel<<<eblocks, 256, 0, stream>>>(esrc, deg, n_edges);
    const int nb = (n_nodes + 1023) / 1024;  // <= 1024 for n_nodes <= 1M
    scan_block_kernel<<<nb, 1024, 0, stream>>>(deg, rowp, bsums, n_nodes);
    scan_tops_kernel<<<1, 1024, 0, stream>>>(bsums, nb);
    add_off_kernel<<<(n_nodes + 255) / 256, 256, 0, stream>>>(
        rowp, cursor, bsums, n_nodes, n_edges);
    placement_kernel<<<eblocks, 256, 0, stream>>>(esrc, edst, ew, cursor, bins,
                                                  n_edges);
    // 3) aggregate + ReLU (writes every output element)
    aggregate_kernel<<<2048, 256, 0, stream>>>(xw, bins, rowp, out, n_nodes);
  } else {
    // Fallback: atomic scatter
    hipMemsetAsync(d_out, 0, (size_t)out_size * sizeof(float), stream);
    edge_scatter_kernel<<<2048, 256, 0, stream>>>(xw, ew, esrc, edst, out,
                                                  n_edges);
    relu_kernel<<<1024, 256, 0, stream>>>(out, out_size / 4);
  }
}

// Round 5
// 379.044 us; speedup vs baseline: 1.4890x; 1.2796x over previous
//
#include <hip/hip_runtime.h>
#include <hip/hip_bf16.h>

#define NDIN 128
#define NDOUT 64
#define BR 256  // rows per GEMM block
#define KC 16   // k-chunk staged in LDS

// ---------------------------------------------------------------------------
// Kernel 1: xw = bf16(x @ W)   (f32 vector GEMM; K=128, N=64)
// 256 threads; block tile 256x64; thread tile 8 rows x 8 cols.
// x chunk staged TRANSPOSED xt[k][row] so a-frags are contiguous b128 reads.
// W fully resident in LDS (32 KB). LDS total 48 KB -> 3 blocks/CU.
// Inner loop: per k, 4 ds_read_b128 feed 64 v_fmac -> VALU-leaning balance.
// ---------------------------------------------------------------------------
__global__ __launch_bounds__(256) void gemm_xw_kernel(
    const float* __restrict__ x, const float* __restrict__ w,
    __hip_bfloat16* __restrict__ xw, int n_nodes) {
  __shared__ float wlds[NDIN][NDOUT];  // 32 KB
  __shared__ float xt[KC][BR];         // 16 KB, transposed chunk
  const int t = threadIdx.x;

  const float4* w4 = (const float4*)w;
  float4* wl4 = (float4*)(&wlds[0][0]);
#pragma unroll
  for (int i = 0; i < (NDIN * NDOUT / 4) / 256; ++i)
    wl4[t + i * 256] = w4[t + i * 256];

  const int row0 = blockIdx.x * BR;
  const int colg = t & 7;   // 8 col-groups x 8 cols
  const int rowg = t >> 3;  // 32 row-groups x 8 rows

  float acc[8][8];
#pragma unroll
  for (int i = 0; i < 8; ++i)
#pragma unroll
    for (int j = 0; j < 8; ++j) acc[i][j] = 0.f;

  for (int kc = 0; kc < NDIN; kc += KC) {
    __syncthreads();  // xt reuse guard (no-op cost on first iter)
    // stage xt[KC][BR]: 1024 float4 global reads, transposed LDS writes
#pragma unroll
    for (int p = 0; p < 4; ++p) {
      const int i = t + p * 256;
      const int r = i >> 2;   // tile row 0..255
      const int c4 = i & 3;   // which float4 of the 16-k chunk
      const int grow = row0 + r;
      float4 v = (grow < n_nodes)
                     ? *(const float4*)(x + (size_t)grow * NDIN + kc + c4 * 4)
                     : make_float4(0.f, 0.f, 0.f, 0.f);
      xt[c4 * 4 + 0][r] = v.x;
      xt[c4 * 4 + 1][r] = v.y;
      xt[c4 * 4 + 2][r] = v.z;
      xt[c4 * 4 + 3][r] = v.w;
    }
    __syncthreads();
#pragma unroll
    for (int k = 0; k < KC; ++k) {
      const float4 a0 = *(const float4*)(&xt[k][rowg * 8]);
      const float4 a1 = *(const float4*)(&xt[k][rowg * 8 + 4]);
      const float4 b0 = *(const float4*)(&wlds[kc + k][colg * 8]);
      const float4 b1 = *(const float4*)(&wlds[kc + k][colg * 8 + 4]);
      const float a[8] = {a0.x, a0.y, a0.z, a0.w, a1.x, a1.y, a1.z, a1.w};
      const float b[8] = {b0.x, b0.y, b0.z, b0.w, b1.x, b1.y, b1.z, b1.w};
#pragma unroll
      for (int i = 0; i < 8; ++i)
#pragma unroll
        for (int j = 0; j < 8; ++j) acc[i][j] += a[i] * b[j];
    }
  }
  // epilogue: bf16 convert, one 16B store per row
#pragma unroll
  for (int i = 0; i < 8; ++i) {
    const int grow = row0 + rowg * 8 + i;
    if (grow < n_nodes) {
      __hip_bfloat16 tmp[8];
#pragma unroll
      for (int j = 0; j < 8; ++j) tmp[j] = __float2bfloat16(acc[i][j]);
      *(uint4*)(xw + (size_t)grow * NDOUT + colg * 8) = *(const uint4*)tmp;
    }
  }
}

// ---------------------------------------------------------------------------
// CSR build: histogram -> exclusive scan (3 kernels) -> placement
// ---------------------------------------------------------------------------
__global__ __launch_bounds__(256) void hist_kernel(const int* __restrict__ src,
                                                   int* __restrict__ deg,
                                                   int n_edges) {
  int e = blockIdx.x * 256 + threadIdx.x;
  if (e < n_edges) atomicAdd(&deg[src[e]], 1);
}

__global__ __launch_bounds__(1024) void scan_block_kernel(
    const int* __restrict__ deg, int* __restrict__ row,
    int* __restrict__ bsums, int n) {
  __shared__ int s[1024];
  const int t = threadIdx.x;
  const int i = blockIdx.x * 1024 + t;
  const int v = (i < n) ? deg[i] : 0;
  s[t] = v;
  __syncthreads();
#pragma unroll
  for (int off = 1; off < 1024; off <<= 1) {
    int add = (t >= off) ? s[t - off] : 0;
    __syncthreads();
    s[t] += add;
    __syncthreads();
  }
  if (i < n) row[i] = s[t] - v;  // exclusive
  if (t == 1023) bsums[blockIdx.x] = s[1023];
}

__global__ __launch_bounds__(1024) void scan_tops_kernel(int* __restrict__ bsums,
                                                         int nb) {
  __shared__ int s[1024];
  const int t = threadIdx.x;
  const int v = (t < nb) ? bsums[t] : 0;
  s[t] = v;
  __syncthreads();
#pragma unroll
  for (int off = 1; off < 1024; off <<= 1) {
    int add = (t >= off) ? s[t - off] : 0;
    __syncthreads();
    s[t] += add;
    __syncthreads();
  }
  if (t < nb) bsums[t] = s[t] - v;  // exclusive over block sums
}

__global__ __launch_bounds__(256) void add_off_kernel(
    int* __restrict__ row, int* __restrict__ cursor,
    const int* __restrict__ bsums, int n, int n_edges) {
  const int i = blockIdx.x * 256 + threadIdx.x;
  if (i < n) {
    const int r = row[i] + bsums[i >> 10];
    row[i] = r;
    cursor[i] = r;
  }
  if (i == 0) row[n] = n_edges;
}

__global__ __launch_bounds__(256) void placement_kernel(
    const int* __restrict__ src, const int* __restrict__ dst,
    const float* __restrict__ ew, int* __restrict__ cursor,
    int2* __restrict__ bins, int n_edges) {
  const int e = blockIdx.x * 256 + threadIdx.x;
  if (e >= n_edges) return;
  const int s = src[e];
  const int p = atomicAdd(&cursor[s], 1);
  int2 b;
  b.x = dst[e];
  b.y = __float_as_int(ew[e]);
  bins[p] = b;
}

// ---------------------------------------------------------------------------
// Aggregate: one wave per node, lane = column. bf16 gather (128 B/edge),
// f32 accumulate, ReLU fused, one coalesced store per node.
// ---------------------------------------------------------------------------
__global__ __launch_bounds__(256) void aggregate_kernel(
    const __hip_bfloat16* __restrict__ xw, const int2* __restrict__ bins,
    const int* __restrict__ row, float* __restrict__ out, int n_nodes) {
  const int lane = threadIdx.x & 63;
  const int wid = (blockIdx.x * 256 + threadIdx.x) >> 6;
  const int nw = (gridDim.x * 256) >> 6;
  for (int n = wid; n < n_nodes; n += nw) {
    const int s0 = row[n], s1 = row[n + 1];
    float acc = 0.f;
    int i = s0;
    for (; i + 4 <= s1; i += 4) {
      const int2 b0 = bins[i], b1 = bins[i + 1];
      const int2 b2 = bins[i + 2], b3 = bins[i + 3];
      const float v0 = __bfloat162float(xw[(size_t)b0.x * NDOUT + lane]);
      const float v1 = __bfloat162float(xw[(size_t)b1.x * NDOUT + lane]);
      const float v2 = __bfloat162float(xw[(size_t)b2.x * NDOUT + lane]);
      const float v3 = __bfloat162float(xw[(size_t)b3.x * NDOUT + lane]);
      acc += __int_as_float(b0.y) * v0 + __int_as_float(b1.y) * v1 +
             __int_as_float(b2.y) * v2 + __int_as_float(b3.y) * v3;
    }
    for (; i < s1; ++i) {
      const int2 b = bins[i];
      acc += __int_as_float(b.y) *
             __bfloat162float(xw[(size_t)b.x * NDOUT + lane]);
    }
    out[(size_t)n * NDOUT + lane] = fmaxf(acc, 0.f);
  }
}

// ---------------------------------------------------------------------------
// Fallback path (ws too small): atomic scatter + relu
// ---------------------------------------------------------------------------
__global__ __launch_bounds__(256) void edge_scatter_kernel(
    const __hip_bfloat16* __restrict__ xw, const float* __restrict__ ew,
    const int* __restrict__ src, const int* __restrict__ dst,
    float* __restrict__ out, int n_edges) {
  const int lane = threadIdx.x & 63;
  const int wid = (blockIdx.x * 256 + threadIdx.x) >> 6;
  const int nw = (gridDim.x * 256) >> 6;
  for (int e0 = wid * 4; e0 < n_edges; e0 += nw * 4) {
    int s[4];
    float v[4];
    bool ok[4];
#pragma unroll
    for (int j = 0; j < 4; ++j) {
      const int e = e0 + j;
      ok[j] = (e < n_edges);
      const int ee = ok[j] ? e : 0;
      s[j] = src[ee];
      const int d = dst[ee];
      v[j] = __bfloat162float(xw[(size_t)d * NDOUT + lane]) * ew[ee];
    }
#pragma unroll
    for (int j = 0; j < 4; ++j) {
      if (ok[j]) unsafeAtomicAdd(out + (size_t)s[j] * NDOUT + lane, v[j]);
    }
  }
}

__global__ __launch_bounds__(256) void relu_kernel(float* __restrict__ out,
                                                   int n4) {
  float4* o4 = (float4*)out;
  int i = blockIdx.x * 256 + threadIdx.x;
  const int stride = gridDim.x * 256;
  for (; i < n4; i += stride) {
    float4 v = o4[i];
    v.x = fmaxf(v.x, 0.f);
    v.y = fmaxf(v.y, 0.f);
    v.z = fmaxf(v.z, 0.f);
    v.w = fmaxf(v.w, 0.f);
    o4[i] = v;
  }
}

extern "C" void kernel_launch(void* const* d_in, const int* in_sizes, int n_in,
                              void* d_out, int out_size, void* d_ws,
                              size_t ws_size, hipStream_t stream) {
  const float* x = (const float*)d_in[0];     // [N, 128]
  const float* ew = (const float*)d_in[1];    // [E]
  const float* w = (const float*)d_in[2];     // [128, 64]
  const int* esrc = (const int*)d_in[3];      // [E]
  const int* edst = (const int*)d_in[4];      // [E]
  float* out = (float*)d_out;                 // [N, 64]

  const int n_nodes = in_sizes[0] / NDIN;
  const int n_edges = in_sizes[1];

  // ws layout:
  //   xw:     N*64 bf16
  //   bins:   E int2
  //   row:    (N+1) int
  //   deg:    N int
  //   cursor: N int
  //   bsums:  1024 int
  char* base = (char*)d_ws;
  size_t off = 0;
  __hip_bfloat16* xw = (__hip_bfloat16*)(base + off);
  off += (size_t)n_nodes * NDOUT * 2;
  off = (off + 15) & ~(size_t)15;
  int2* bins = (int2*)(base + off); off += (size_t)n_edges * 8;
  int* rowp = (int*)(base + off); off += (size_t)(n_nodes + 1) * 4;
  int* deg = (int*)(base + off); off += (size_t)n_nodes * 4;
  int* cursor = (int*)(base + off); off += (size_t)n_nodes * 4;
  int* bsums = (int*)(base + off); off += 4096;
  const bool csr_ok = (ws_size >= off);

  // 1) xw = bf16(x @ W)
  const int gblocks = (n_nodes + BR - 1) / BR;
  gemm_xw_kernel<<<gblocks, 256, 0, stream>>>(x, w, xw, n_nodes);

  const int eblocks = (n_edges + 255) / 256;
  if (csr_ok) {
    // 2) CSR build
    hipMemsetAsync(deg, 0, (size_t)n_nodes * 4, stream);
    hist_kernel<<<eblocks, 256, 0, stream>>>(esrc, deg, n_edges);
    const int nb = (n_nodes + 1023) / 1024;  // <= 1024 for n_nodes <= 1M
    scan_block_kernel<<<nb, 1024, 0, stream>>>(deg, rowp, bsums, n_nodes);
    scan_tops_kernel<<<1, 1024, 0, stream>>>(bsums, nb);
    add_off_kernel<<<(n_nodes + 255) / 256, 256, 0, stream>>>(
        rowp, cursor, bsums, n_nodes, n_edges);
    placement_kernel<<<eblocks, 256, 0, stream>>>(esrc, edst, ew, cursor, bins,
                                                  n_edges);
    // 3) aggregate + ReLU (writes every output element)
    aggregate_kernel<<<2048, 256, 0, stream>>>(xw, bins, rowp, out, n_nodes);
  } else {
    // Fallback: atomic scatter
    hipMemsetAsync(d_out, 0, (size_t)out_size * sizeof(float), stream);
    edge_scatter_kernel<<<2048, 256, 0, stream>>>(xw, ew, esrc, edst, out,
                                                  n_edges);
    relu_kernel<<<1024, 256, 0, stream>>>(out, out_size / 4);
  }
}

// Round 6
// 331.388 us; speedup vs baseline: 1.7032x; 1.1438x over previous
//
#include <hip/hip_runtime.h>
#include <hip/hip_bf16.h>

#define NDIN 128
#define NDOUT 64
#define BR 256  // rows per GEMM block
#define KC 16   // k-chunk staged in LDS

// ---------------------------------------------------------------------------
// Kernel 1: xw = bf16(x @ W)   (f32 vector GEMM; K=128, N=64)
// 256 threads; block tile 256x64; thread tile 8x8. x chunk staged transposed.
// ---------------------------------------------------------------------------
__global__ __launch_bounds__(256) void gemm_xw_kernel(
    const float* __restrict__ x, const float* __restrict__ w,
    __hip_bfloat16* __restrict__ xw, int n_nodes) {
  __shared__ float wlds[NDIN][NDOUT];  // 32 KB
  __shared__ float xt[KC][BR];         // 16 KB, transposed chunk
  const int t = threadIdx.x;

  const float4* w4 = (const float4*)w;
  float4* wl4 = (float4*)(&wlds[0][0]);
#pragma unroll
  for (int i = 0; i < (NDIN * NDOUT / 4) / 256; ++i)
    wl4[t + i * 256] = w4[t + i * 256];

  const int row0 = blockIdx.x * BR;
  const int colg = t & 7;   // 8 col-groups x 8 cols
  const int rowg = t >> 3;  // 32 row-groups x 8 rows

  float acc[8][8];
#pragma unroll
  for (int i = 0; i < 8; ++i)
#pragma unroll
    for (int j = 0; j < 8; ++j) acc[i][j] = 0.f;

  for (int kc = 0; kc < NDIN; kc += KC) {
    __syncthreads();
#pragma unroll
    for (int p = 0; p < 4; ++p) {
      const int i = t + p * 256;
      const int r = i >> 2;
      const int c4 = i & 3;
      const int grow = row0 + r;
      float4 v = (grow < n_nodes)
                     ? *(const float4*)(x + (size_t)grow * NDIN + kc + c4 * 4)
                     : make_float4(0.f, 0.f, 0.f, 0.f);
      xt[c4 * 4 + 0][r] = v.x;
      xt[c4 * 4 + 1][r] = v.y;
      xt[c4 * 4 + 2][r] = v.z;
      xt[c4 * 4 + 3][r] = v.w;
    }
    __syncthreads();
#pragma unroll
    for (int k = 0; k < KC; ++k) {
      const float4 a0 = *(const float4*)(&xt[k][rowg * 8]);
      const float4 a1 = *(const float4*)(&xt[k][rowg * 8 + 4]);
      const float4 b0 = *(const float4*)(&wlds[kc + k][colg * 8]);
      const float4 b1 = *(const float4*)(&wlds[kc + k][colg * 8 + 4]);
      const float a[8] = {a0.x, a0.y, a0.z, a0.w, a1.x, a1.y, a1.z, a1.w};
      const float b[8] = {b0.x, b0.y, b0.z, b0.w, b1.x, b1.y, b1.z, b1.w};
#pragma unroll
      for (int i = 0; i < 8; ++i)
#pragma unroll
        for (int j = 0; j < 8; ++j) acc[i][j] += a[i] * b[j];
    }
  }
#pragma unroll
  for (int i = 0; i < 8; ++i) {
    const int grow = row0 + rowg * 8 + i;
    if (grow < n_nodes) {
      __hip_bfloat16 tmp[8];
#pragma unroll
      for (int j = 0; j < 8; ++j) tmp[j] = __float2bfloat16(acc[i][j]);
      *(uint4*)(xw + (size_t)grow * NDOUT + colg * 8) = *(const uint4*)tmp;
    }
  }
}

// ---------------------------------------------------------------------------
// K2: histogram + per-edge rank. The atomic's return value IS the rank of
// edge e among edges sharing its src (arrival order). rnk write is coalesced.
// ---------------------------------------------------------------------------
__global__ __launch_bounds__(256) void hist_rank_kernel(
    const int* __restrict__ src, int* __restrict__ deg,
    unsigned short* __restrict__ rnk, int n_edges) {
  const int stride = gridDim.x * 256;
  for (int e = blockIdx.x * 256 + threadIdx.x; e < n_edges; e += stride) {
    const int r = atomicAdd(&deg[src[e]], 1);
    rnk[e] = (unsigned short)r;
  }
}

// ---------------------------------------------------------------------------
// Exclusive scan of deg -> row (3 kernels)
// ---------------------------------------------------------------------------
__global__ __launch_bounds__(1024) void scan_block_kernel(
    const int* __restrict__ deg, int* __restrict__ row,
    int* __restrict__ bsums, int n) {
  __shared__ int s[1024];
  const int t = threadIdx.x;
  const int i = blockIdx.x * 1024 + t;
  const int v = (i < n) ? deg[i] : 0;
  s[t] = v;
  __syncthreads();
#pragma unroll
  for (int off = 1; off < 1024; off <<= 1) {
    int add = (t >= off) ? s[t - off] : 0;
    __syncthreads();
    s[t] += add;
    __syncthreads();
  }
  if (i < n) row[i] = s[t] - v;  // exclusive
  if (t == 1023) bsums[blockIdx.x] = s[1023];
}

__global__ __launch_bounds__(1024) void scan_tops_kernel(int* __restrict__ bsums,
                                                         int nb) {
  __shared__ int s[1024];
  const int t = threadIdx.x;
  const int v = (t < nb) ? bsums[t] : 0;
  s[t] = v;
  __syncthreads();
#pragma unroll
  for (int off = 1; off < 1024; off <<= 1) {
    int add = (t >= off) ? s[t - off] : 0;
    __syncthreads();
    s[t] += add;
    __syncthreads();
  }
  if (t < nb) bsums[t] = s[t] - v;
}

__global__ __launch_bounds__(256) void add_off_kernel(
    int* __restrict__ row, const int* __restrict__ bsums, int n, int n_edges) {
  const int i = blockIdx.x * 256 + threadIdx.x;
  if (i < n) row[i] += bsums[i >> 10];
  if (i == 0) row[n] = n_edges;
}

// ---------------------------------------------------------------------------
// K3: placement, NO atomics: perm[row[src[e]] + rnk[e]] = e  (bijection)
// ---------------------------------------------------------------------------
__global__ __launch_bounds__(256) void place_kernel(
    const int* __restrict__ src, const int* __restrict__ row,
    const unsigned short* __restrict__ rnk, int* __restrict__ perm,
    int n_edges) {
  const int stride = gridDim.x * 256;
  for (int e = blockIdx.x * 256 + threadIdx.x; e < n_edges; e += stride) {
    perm[row[src[e]] + rnk[e]] = e;
  }
}

// ---------------------------------------------------------------------------
// K4: aggregate. One wave per node, lane = column. perm/dst/ew reads are
// wave-broadcast (L2); xw row gathers are bf16 (128 B/edge). ReLU fused.
// ---------------------------------------------------------------------------
__global__ __launch_bounds__(256) void aggregate_kernel(
    const __hip_bfloat16* __restrict__ xw, const int* __restrict__ perm,
    const int* __restrict__ dst, const float* __restrict__ ew,
    const int* __restrict__ row, float* __restrict__ out, int n_nodes) {
  const int lane = threadIdx.x & 63;
  const int wid = (blockIdx.x * 256 + threadIdx.x) >> 6;
  const int nw = (gridDim.x * 256) >> 6;
  for (int n = wid; n < n_nodes; n += nw) {
    const int s0 = row[n], s1 = row[n + 1];
    float acc = 0.f;
    int i = s0;
    for (; i + 4 <= s1; i += 4) {
      const int e0 = perm[i], e1 = perm[i + 1];
      const int e2 = perm[i + 2], e3 = perm[i + 3];
      const float w0 = ew[e0], w1 = ew[e1], w2 = ew[e2], w3 = ew[e3];
      const int d0 = dst[e0], d1 = dst[e1], d2 = dst[e2], d3 = dst[e3];
      const float v0 = __bfloat162float(xw[(size_t)d0 * NDOUT + lane]);
      const float v1 = __bfloat162float(xw[(size_t)d1 * NDOUT + lane]);
      const float v2 = __bfloat162float(xw[(size_t)d2 * NDOUT + lane]);
      const float v3 = __bfloat162float(xw[(size_t)d3 * NDOUT + lane]);
      acc += w0 * v0 + w1 * v1 + w2 * v2 + w3 * v3;
    }
    for (; i < s1; ++i) {
      const int e = perm[i];
      acc += ew[e] * __bfloat162float(xw[(size_t)dst[e] * NDOUT + lane]);
    }
    out[(size_t)n * NDOUT + lane] = fmaxf(acc, 0.f);
  }
}

// ---------------------------------------------------------------------------
// Fallback path (ws too small): atomic scatter + relu
// ---------------------------------------------------------------------------
__global__ __launch_bounds__(256) void edge_scatter_kernel(
    const __hip_bfloat16* __restrict__ xw, const float* __restrict__ ew,
    const int* __restrict__ src, const int* __restrict__ dst,
    float* __restrict__ out, int n_edges) {
  const int lane = threadIdx.x & 63;
  const int wid = (blockIdx.x * 256 + threadIdx.x) >> 6;
  const int nw = (gridDim.x * 256) >> 6;
  for (int e0 = wid * 4; e0 < n_edges; e0 += nw * 4) {
    int s[4];
    float v[4];
    bool ok[4];
#pragma unroll
    for (int j = 0; j < 4; ++j) {
      const int e = e0 + j;
      ok[j] = (e < n_edges);
      const int ee = ok[j] ? e : 0;
      s[j] = src[ee];
      v[j] = __bfloat162float(xw[(size_t)dst[ee] * NDOUT + lane]) * ew[ee];
    }
#pragma unroll
    for (int j = 0; j < 4; ++j) {
      if (ok[j]) unsafeAtomicAdd(out + (size_t)s[j] * NDOUT + lane, v[j]);
    }
  }
}

__global__ __launch_bounds__(256) void relu_kernel(float* __restrict__ out,
                                                   int n4) {
  float4* o4 = (float4*)out;
  int i = blockIdx.x * 256 + threadIdx.x;
  const int stride = gridDim.x * 256;
  for (; i < n4; i += stride) {
    float4 v = o4[i];
    v.x = fmaxf(v.x, 0.f);
    v.y = fmaxf(v.y, 0.f);
    v.z = fmaxf(v.z, 0.f);
    v.w = fmaxf(v.w, 0.f);
    o4[i] = v;
  }
}

extern "C" void kernel_launch(void* const* d_in, const int* in_sizes, int n_in,
                              void* d_out, int out_size, void* d_ws,
                              size_t ws_size, hipStream_t stream) {
  const float* x = (const float*)d_in[0];     // [N, 128]
  const float* ew = (const float*)d_in[1];    // [E]
  const float* w = (const float*)d_in[2];     // [128, 64]
  const int* esrc = (const int*)d_in[3];      // [E]
  const int* edst = (const int*)d_in[4];      // [E]
  float* out = (float*)d_out;                 // [N, 64]

  const int n_nodes = in_sizes[0] / NDIN;
  const int n_edges = in_sizes[1];

  // ws layout:
  //   xw:   N*64 bf16
  //   perm: E int
  //   rnk:  E u16
  //   row:  (N+1) int
  //   deg:  N int
  //   bsums: 1024 int
  char* base = (char*)d_ws;
  size_t off = 0;
  __hip_bfloat16* xw = (__hip_bfloat16*)(base + off);
  off += (size_t)n_nodes * NDOUT * 2;
  off = (off + 15) & ~(size_t)15;
  int* perm = (int*)(base + off); off += (size_t)n_edges * 4;
  unsigned short* rnk = (unsigned short*)(base + off);
  off += (size_t)n_edges * 2;
  off = (off + 15) & ~(size_t)15;
  int* rowp = (int*)(base + off); off += (size_t)(n_nodes + 1) * 4;
  int* deg = (int*)(base + off); off += (size_t)n_nodes * 4;
  int* bsums = (int*)(base + off); off += 4096;
  const bool csr_ok = (ws_size >= off);

  // 1) xw = bf16(x @ W)
  const int gblocks = (n_nodes + BR - 1) / BR;
  gemm_xw_kernel<<<gblocks, 256, 0, stream>>>(x, w, xw, n_nodes);

  if (csr_ok) {
    // 2) CSR build without placement atomics
    hipMemsetAsync(deg, 0, (size_t)n_nodes * 4, stream);
    hist_rank_kernel<<<2048, 256, 0, stream>>>(esrc, deg, rnk, n_edges);
    const int nb = (n_nodes + 1023) / 1024;
    scan_block_kernel<<<nb, 1024, 0, stream>>>(deg, rowp, bsums, n_nodes);
    scan_tops_kernel<<<1, 1024, 0, stream>>>(bsums, nb);
    add_off_kernel<<<(n_nodes + 255) / 256, 256, 0, stream>>>(rowp, bsums,
                                                              n_nodes, n_edges);
    place_kernel<<<2048, 256, 0, stream>>>(esrc, rowp, rnk, perm, n_edges);
    // 3) aggregate + ReLU
    aggregate_kernel<<<2048, 256, 0, stream>>>(xw, perm, edst, ew, rowp, out,
                                               n_nodes);
  } else {
    hipMemsetAsync(d_out, 0, (size_t)out_size * sizeof(float), stream);
    edge_scatter_kernel<<<2048, 256, 0, stream>>>(xw, ew, esrc, edst, out,
                                                  n_edges);
    relu_kernel<<<1024, 256, 0, stream>>>(out, out_size / 4);
  }
}

// Round 7
// 320.208 us; speedup vs baseline: 1.7626x; 1.0349x over previous
//
#include <hip/hip_runtime.h>
#include <hip/hip_bf16.h>

#define NDIN 128
#define NDOUT 64
#define BR 256  // rows per GEMM block
#define KC 16   // k-chunk staged in LDS

// ---------------------------------------------------------------------------
// Kernel 1: xw = bf16(x @ W)   (f32 vector GEMM; K=128, N=64)
// 256 threads; block tile 256x64; thread tile 8x8. x chunk staged transposed.
// ---------------------------------------------------------------------------
__global__ __launch_bounds__(256) void gemm_xw_kernel(
    const float* __restrict__ x, const float* __restrict__ w,
    __hip_bfloat16* __restrict__ xw, int n_nodes) {
  __shared__ float wlds[NDIN][NDOUT];  // 32 KB
  __shared__ float xt[KC][BR];         // 16 KB, transposed chunk
  const int t = threadIdx.x;

  const float4* w4 = (const float4*)w;
  float4* wl4 = (float4*)(&wlds[0][0]);
#pragma unroll
  for (int i = 0; i < (NDIN * NDOUT / 4) / 256; ++i)
    wl4[t + i * 256] = w4[t + i * 256];

  const int row0 = blockIdx.x * BR;
  const int colg = t & 7;   // 8 col-groups x 8 cols
  const int rowg = t >> 3;  // 32 row-groups x 8 rows

  float acc[8][8];
#pragma unroll
  for (int i = 0; i < 8; ++i)
#pragma unroll
    for (int j = 0; j < 8; ++j) acc[i][j] = 0.f;

  for (int kc = 0; kc < NDIN; kc += KC) {
    __syncthreads();
#pragma unroll
    for (int p = 0; p < 4; ++p) {
      const int i = t + p * 256;
      const int r = i >> 2;
      const int c4 = i & 3;
      const int grow = row0 + r;
      float4 v = (grow < n_nodes)
                     ? *(const float4*)(x + (size_t)grow * NDIN + kc + c4 * 4)
                     : make_float4(0.f, 0.f, 0.f, 0.f);
      xt[c4 * 4 + 0][r] = v.x;
      xt[c4 * 4 + 1][r] = v.y;
      xt[c4 * 4 + 2][r] = v.z;
      xt[c4 * 4 + 3][r] = v.w;
    }
    __syncthreads();
#pragma unroll
    for (int k = 0; k < KC; ++k) {
      const float4 a0 = *(const float4*)(&xt[k][rowg * 8]);
      const float4 a1 = *(const float4*)(&xt[k][rowg * 8 + 4]);
      const float4 b0 = *(const float4*)(&wlds[kc + k][colg * 8]);
      const float4 b1 = *(const float4*)(&wlds[kc + k][colg * 8 + 4]);
      const float a[8] = {a0.x, a0.y, a0.z, a0.w, a1.x, a1.y, a1.z, a1.w};
      const float b[8] = {b0.x, b0.y, b0.z, b0.w, b1.x, b1.y, b1.z, b1.w};
#pragma unroll
      for (int i = 0; i < 8; ++i)
#pragma unroll
        for (int j = 0; j < 8; ++j) acc[i][j] += a[i] * b[j];
    }
  }
#pragma unroll
  for (int i = 0; i < 8; ++i) {
    const int grow = row0 + rowg * 8 + i;
    if (grow < n_nodes) {
      __hip_bfloat16 tmp[8];
#pragma unroll
      for (int j = 0; j < 8; ++j) tmp[j] = __float2bfloat16(acc[i][j]);
      *(uint4*)(xw + (size_t)grow * NDOUT + colg * 8) = *(const uint4*)tmp;
    }
  }
}

// ---------------------------------------------------------------------------
// K2: histogram + per-edge rank (atomic return value = rank within src bin)
// ---------------------------------------------------------------------------
__global__ __launch_bounds__(256) void hist_rank_kernel(
    const int* __restrict__ src, int* __restrict__ deg,
    unsigned short* __restrict__ rnk, int n_edges) {
  const int stride = gridDim.x * 256;
  for (int e = blockIdx.x * 256 + threadIdx.x; e < n_edges; e += stride) {
    const int r = atomicAdd(&deg[src[e]], 1);
    rnk[e] = (unsigned short)r;
  }
}

// ---------------------------------------------------------------------------
// Exclusive scan of deg -> row (3 kernels)
// ---------------------------------------------------------------------------
__global__ __launch_bounds__(1024) void scan_block_kernel(
    const int* __restrict__ deg, int* __restrict__ row,
    int* __restrict__ bsums, int n) {
  __shared__ int s[1024];
  const int t = threadIdx.x;
  const int i = blockIdx.x * 1024 + t;
  const int v = (i < n) ? deg[i] : 0;
  s[t] = v;
  __syncthreads();
#pragma unroll
  for (int off = 1; off < 1024; off <<= 1) {
    int add = (t >= off) ? s[t - off] : 0;
    __syncthreads();
    s[t] += add;
    __syncthreads();
  }
  if (i < n) row[i] = s[t] - v;  // exclusive
  if (t == 1023) bsums[blockIdx.x] = s[1023];
}

__global__ __launch_bounds__(1024) void scan_tops_kernel(int* __restrict__ bsums,
                                                         int nb) {
  __shared__ int s[1024];
  const int t = threadIdx.x;
  const int v = (t < nb) ? bsums[t] : 0;
  s[t] = v;
  __syncthreads();
#pragma unroll
  for (int off = 1; off < 1024; off <<= 1) {
    int add = (t >= off) ? s[t - off] : 0;
    __syncthreads();
    s[t] += add;
    __syncthreads();
  }
  if (t < nb) bsums[t] = s[t] - v;
}

__global__ __launch_bounds__(256) void add_off_kernel(
    int* __restrict__ row, const int* __restrict__ bsums, int n, int n_edges) {
  const int i = blockIdx.x * 256 + threadIdx.x;
  if (i < n) row[i] += bsums[i >> 10];
  if (i == 0) row[n] = n_edges;
}

// ---------------------------------------------------------------------------
// K3: placement, NO atomics: bins[row[src[e]] + rnk[e]] = {dst[e], ew[e]}
// All reads coalesced except the 4B row[] gather (400 KB, L2-resident).
// ---------------------------------------------------------------------------
__global__ __launch_bounds__(256) void place_kernel(
    const int* __restrict__ src, const int* __restrict__ dst,
    const float* __restrict__ ew, const int* __restrict__ row,
    const unsigned short* __restrict__ rnk, int2* __restrict__ bins,
    int n_edges) {
  const int stride = gridDim.x * 256;
  for (int e = blockIdx.x * 256 + threadIdx.x; e < n_edges; e += stride) {
    int2 b;
    b.x = dst[e];
    b.y = __float_as_int(ew[e]);
    bins[row[src[e]] + rnk[e]] = b;
  }
}

// ---------------------------------------------------------------------------
// K4: aggregate. One wave per node, lane = column. bins reads are sequential
// per-node (L2-friendly, wave-broadcast); xw row gathers bf16 (128 B/edge),
// 8 independent gathers in flight per iteration. ReLU fused.
// ---------------------------------------------------------------------------
__global__ __launch_bounds__(256) void aggregate_kernel(
    const __hip_bfloat16* __restrict__ xw, const int2* __restrict__ bins,
    const int* __restrict__ row, float* __restrict__ out, int n_nodes) {
  const int lane = threadIdx.x & 63;
  const int wid = (blockIdx.x * 256 + threadIdx.x) >> 6;
  const int nw = (gridDim.x * 256) >> 6;
  for (int n = wid; n < n_nodes; n += nw) {
    const int s0 = row[n], s1 = row[n + 1];
    float acc = 0.f;
    int i = s0;
    for (; i + 8 <= s1; i += 8) {
      int2 b[8];
#pragma unroll
      for (int j = 0; j < 8; ++j) b[j] = bins[i + j];
      float v[8];
#pragma unroll
      for (int j = 0; j < 8; ++j)
        v[j] = __bfloat162float(xw[(size_t)b[j].x * NDOUT + lane]);
#pragma unroll
      for (int j = 0; j < 8; ++j) acc += __int_as_float(b[j].y) * v[j];
    }
    for (; i < s1; ++i) {
      const int2 b = bins[i];
      acc += __int_as_float(b.y) *
             __bfloat162float(xw[(size_t)b.x * NDOUT + lane]);
    }
    out[(size_t)n * NDOUT + lane] = fmaxf(acc, 0.f);
  }
}

// ---------------------------------------------------------------------------
// Fallback path (ws too small): atomic scatter + relu
// ---------------------------------------------------------------------------
__global__ __launch_bounds__(256) void edge_scatter_kernel(
    const __hip_bfloat16* __restrict__ xw, const float* __restrict__ ew,
    const int* __restrict__ src, const int* __restrict__ dst,
    float* __restrict__ out, int n_edges) {
  const int lane = threadIdx.x & 63;
  const int wid = (blockIdx.x * 256 + threadIdx.x) >> 6;
  const int nw = (gridDim.x * 256) >> 6;
  for (int e0 = wid * 4; e0 < n_edges; e0 += nw * 4) {
    int s[4];
    float v[4];
    bool ok[4];
#pragma unroll
    for (int j = 0; j < 4; ++j) {
      const int e = e0 + j;
      ok[j] = (e < n_edges);
      const int ee = ok[j] ? e : 0;
      s[j] = src[ee];
      v[j] = __bfloat162float(xw[(size_t)dst[ee] * NDOUT + lane]) * ew[ee];
    }
#pragma unroll
    for (int j = 0; j < 4; ++j) {
      if (ok[j]) unsafeAtomicAdd(out + (size_t)s[j] * NDOUT + lane, v[j]);
    }
  }
}

__global__ __launch_bounds__(256) void relu_kernel(float* __restrict__ out,
                                                   int n4) {
  float4* o4 = (float4*)out;
  int i = blockIdx.x * 256 + threadIdx.x;
  const int stride = gridDim.x * 256;
  for (; i < n4; i += stride) {
    float4 v = o4[i];
    v.x = fmaxf(v.x, 0.f);
    v.y = fmaxf(v.y, 0.f);
    v.z = fmaxf(v.z, 0.f);
    v.w = fmaxf(v.w, 0.f);
    o4[i] = v;
  }
}

extern "C" void kernel_launch(void* const* d_in, const int* in_sizes, int n_in,
                              void* d_out, int out_size, void* d_ws,
                              size_t ws_size, hipStream_t stream) {
  const float* x = (const float*)d_in[0];     // [N, 128]
  const float* ew = (const float*)d_in[1];    // [E]
  const float* w = (const float*)d_in[2];     // [128, 64]
  const int* esrc = (const int*)d_in[3];      // [E]
  const int* edst = (const int*)d_in[4];      // [E]
  float* out = (float*)d_out;                 // [N, 64]

  const int n_nodes = in_sizes[0] / NDIN;
  const int n_edges = in_sizes[1];

  // ws layout:
  //   xw:   N*64 bf16
  //   bins: E int2
  //   rnk:  E u16
  //   row:  (N+1) int
  //   deg:  N int
  //   bsums: 1024 int
  char* base = (char*)d_ws;
  size_t off = 0;
  __hip_bfloat16* xw = (__hip_bfloat16*)(base + off);
  off += (size_t)n_nodes * NDOUT * 2;
  off = (off + 15) & ~(size_t)15;
  int2* bins = (int2*)(base + off); off += (size_t)n_edges * 8;
  unsigned short* rnk = (unsigned short*)(base + off);
  off += (size_t)n_edges * 2;
  off = (off + 15) & ~(size_t)15;
  int* rowp = (int*)(base + off); off += (size_t)(n_nodes + 1) * 4;
  int* deg = (int*)(base + off); off += (size_t)n_nodes * 4;
  int* bsums = (int*)(base + off); off += 4096;
  const bool csr_ok = (ws_size >= off);

  // 1) xw = bf16(x @ W)
  const int gblocks = (n_nodes + BR - 1) / BR;
  gemm_xw_kernel<<<gblocks, 256, 0, stream>>>(x, w, xw, n_nodes);

  if (csr_ok) {
    // 2) CSR build without placement atomics
    hipMemsetAsync(deg, 0, (size_t)n_nodes * 4, stream);
    hist_rank_kernel<<<4096, 256, 0, stream>>>(esrc, deg, rnk, n_edges);
    const int nb = (n_nodes + 1023) / 1024;
    scan_block_kernel<<<nb, 1024, 0, stream>>>(deg, rowp, bsums, n_nodes);
    scan_tops_kernel<<<1, 1024, 0, stream>>>(bsums, nb);
    add_off_kernel<<<(n_nodes + 255) / 256, 256, 0, stream>>>(rowp, bsums,
                                                              n_nodes, n_edges);
    place_kernel<<<4096, 256, 0, stream>>>(esrc, edst, ew, rowp, rnk, bins,
                                           n_edges);
    // 3) aggregate + ReLU
    aggregate_kernel<<<4096, 256, 0, stream>>>(xw, bins, rowp, out, n_nodes);
  } else {
    hipMemsetAsync(d_out, 0, (size_t)out_size * sizeof(float), stream);
    edge_scatter_kernel<<<2048, 256, 0, stream>>>(xw, ew, esrc, edst, out,
                                                  n_edges);
    relu_kernel<<<1024, 256, 0, stream>>>(out, out_size / 4);
  }
}

// Round 8
// 307.424 us; speedup vs baseline: 1.8359x; 1.0416x over previous
//
#include <hip/hip_runtime.h>
#include <hip/hip_bf16.h>

#define NDIN 128
#define NDOUT 64
#define BR 256  // rows per GEMM block
#define KC 16   // k-chunk staged in LDS

// ---------------------------------------------------------------------------
// Kernel 1: xw = bf16(x @ W)   (f32 vector GEMM; K=128, N=64)
// 256 threads; block tile 256x64; thread tile 8x8. x chunk staged transposed.
// ---------------------------------------------------------------------------
__global__ __launch_bounds__(256) void gemm_xw_kernel(
    const float* __restrict__ x, const float* __restrict__ w,
    __hip_bfloat16* __restrict__ xw, int n_nodes) {
  __shared__ float wlds[NDIN][NDOUT];  // 32 KB
  __shared__ float xt[KC][BR];         // 16 KB, transposed chunk
  const int t = threadIdx.x;

  const float4* w4 = (const float4*)w;
  float4* wl4 = (float4*)(&wlds[0][0]);
#pragma unroll
  for (int i = 0; i < (NDIN * NDOUT / 4) / 256; ++i)
    wl4[t + i * 256] = w4[t + i * 256];

  const int row0 = blockIdx.x * BR;
  const int colg = t & 7;   // 8 col-groups x 8 cols
  const int rowg = t >> 3;  // 32 row-groups x 8 rows

  float acc[8][8];
#pragma unroll
  for (int i = 0; i < 8; ++i)
#pragma unroll
    for (int j = 0; j < 8; ++j) acc[i][j] = 0.f;

  for (int kc = 0; kc < NDIN; kc += KC) {
    __syncthreads();
#pragma unroll
    for (int p = 0; p < 4; ++p) {
      const int i = t + p * 256;
      const int r = i >> 2;
      const int c4 = i & 3;
      const int grow = row0 + r;
      float4 v = (grow < n_nodes)
                     ? *(const float4*)(x + (size_t)grow * NDIN + kc + c4 * 4)
                     : make_float4(0.f, 0.f, 0.f, 0.f);
      xt[c4 * 4 + 0][r] = v.x;
      xt[c4 * 4 + 1][r] = v.y;
      xt[c4 * 4 + 2][r] = v.z;
      xt[c4 * 4 + 3][r] = v.w;
    }
    __syncthreads();
#pragma unroll
    for (int k = 0; k < KC; ++k) {
      const float4 a0 = *(const float4*)(&xt[k][rowg * 8]);
      const float4 a1 = *(const float4*)(&xt[k][rowg * 8 + 4]);
      const float4 b0 = *(const float4*)(&wlds[kc + k][colg * 8]);
      const float4 b1 = *(const float4*)(&wlds[kc + k][colg * 8 + 4]);
      const float a[8] = {a0.x, a0.y, a0.z, a0.w, a1.x, a1.y, a1.z, a1.w};
      const float b[8] = {b0.x, b0.y, b0.z, b0.w, b1.x, b1.y, b1.z, b1.w};
#pragma unroll
      for (int i = 0; i < 8; ++i)
#pragma unroll
        for (int j = 0; j < 8; ++j) acc[i][j] += a[i] * b[j];
    }
  }
#pragma unroll
  for (int i = 0; i < 8; ++i) {
    const int grow = row0 + rowg * 8 + i;
    if (grow < n_nodes) {
      __hip_bfloat16 tmp[8];
#pragma unroll
      for (int j = 0; j < 8; ++j) tmp[j] = __float2bfloat16(acc[i][j]);
      *(uint4*)(xw + (size_t)grow * NDOUT + colg * 8) = *(const uint4*)tmp;
    }
  }
}

// ---------------------------------------------------------------------------
// K2: histogram + per-edge rank. 4 CONSECUTIVE edges per thread: coalesced
// int4 src load, 4 independent atomics in flight (one vmcnt wait for all),
// one ushort4 rank store. Atomic return value = rank within src bin.
// ---------------------------------------------------------------------------
__global__ __launch_bounds__(256) void hist_rank_kernel(
    const int* __restrict__ src, int* __restrict__ deg,
    unsigned short* __restrict__ rnk, int n_edges) {
  const int t = blockIdx.x * 256 + threadIdx.x;
  const int base = t * 4;
  if (base + 4 <= n_edges) {
    const int4 s4 = *(const int4*)(src + base);
    const int r0 = atomicAdd(&deg[s4.x], 1);
    const int r1 = atomicAdd(&deg[s4.y], 1);
    const int r2 = atomicAdd(&deg[s4.z], 1);
    const int r3 = atomicAdd(&deg[s4.w], 1);
    ushort4 r;
    r.x = (unsigned short)r0;
    r.y = (unsigned short)r1;
    r.z = (unsigned short)r2;
    r.w = (unsigned short)r3;
    *(ushort4*)(rnk + base) = r;
  } else if (base < n_edges) {
    for (int e = base; e < n_edges; ++e)
      rnk[e] = (unsigned short)atomicAdd(&deg[src[e]], 1);
  }
}

// ---------------------------------------------------------------------------
// Exclusive scan of deg -> row (3 kernels)
// ---------------------------------------------------------------------------
__global__ __launch_bounds__(1024) void scan_block_kernel(
    const int* __restrict__ deg, int* __restrict__ row,
    int* __restrict__ bsums, int n) {
  __shared__ int s[1024];
  const int t = threadIdx.x;
  const int i = blockIdx.x * 1024 + t;
  const int v = (i < n) ? deg[i] : 0;
  s[t] = v;
  __syncthreads();
#pragma unroll
  for (int off = 1; off < 1024; off <<= 1) {
    int add = (t >= off) ? s[t - off] : 0;
    __syncthreads();
    s[t] += add;
    __syncthreads();
  }
  if (i < n) row[i] = s[t] - v;  // exclusive
  if (t == 1023) bsums[blockIdx.x] = s[1023];
}

__global__ __launch_bounds__(1024) void scan_tops_kernel(int* __restrict__ bsums,
                                                         int nb) {
  __shared__ int s[1024];
  const int t = threadIdx.x;
  const int v = (t < nb) ? bsums[t] : 0;
  s[t] = v;
  __syncthreads();
#pragma unroll
  for (int off = 1; off < 1024; off <<= 1) {
    int add = (t >= off) ? s[t - off] : 0;
    __syncthreads();
    s[t] += add;
    __syncthreads();
  }
  if (t < nb) bsums[t] = s[t] - v;
}

__global__ __launch_bounds__(256) void add_off_kernel(
    int* __restrict__ row, const int* __restrict__ bsums, int n, int n_edges) {
  const int i = blockIdx.x * 256 + threadIdx.x;
  if (i < n) row[i] += bsums[i >> 10];
  if (i == 0) row[n] = n_edges;
}

// ---------------------------------------------------------------------------
// K3: placement, NO atomics: bins[row[src[e]] + rnk[e]] = {dst[e], ew[e]}
// 4 consecutive edges per thread: vectorized coalesced input loads, 4
// independent row gathers then 4 independent scattered stores in flight.
// ---------------------------------------------------------------------------
__global__ __launch_bounds__(256) void place_kernel(
    const int* __restrict__ src, const int* __restrict__ dst,
    const float* __restrict__ ew, const int* __restrict__ row,
    const unsigned short* __restrict__ rnk, int2* __restrict__ bins,
    int n_edges) {
  const int t = blockIdx.x * 256 + threadIdx.x;
  const int base = t * 4;
  if (base + 4 <= n_edges) {
    const int4 s4 = *(const int4*)(src + base);
    const int4 d4 = *(const int4*)(dst + base);
    const float4 w4 = *(const float4*)(ew + base);
    const ushort4 k4 = *(const ushort4*)(rnk + base);
    const int p0 = row[s4.x] + k4.x;
    const int p1 = row[s4.y] + k4.y;
    const int p2 = row[s4.z] + k4.z;
    const int p3 = row[s4.w] + k4.w;
    bins[p0] = make_int2(d4.x, __float_as_int(w4.x));
    bins[p1] = make_int2(d4.y, __float_as_int(w4.y));
    bins[p2] = make_int2(d4.z, __float_as_int(w4.z));
    bins[p3] = make_int2(d4.w, __float_as_int(w4.w));
  } else if (base < n_edges) {
    for (int e = base; e < n_edges; ++e)
      bins[row[src[e]] + rnk[e]] = make_int2(dst[e], __float_as_int(ew[e]));
  }
}

// ---------------------------------------------------------------------------
// K4: aggregate. One wave per node, lane = column. bins reads sequential
// per-node; xw row gathers bf16 (128 B/edge), 8 in flight. ReLU fused.
// ---------------------------------------------------------------------------
__global__ __launch_bounds__(256) void aggregate_kernel(
    const __hip_bfloat16* __restrict__ xw, const int2* __restrict__ bins,
    const int* __restrict__ row, float* __restrict__ out, int n_nodes) {
  const int lane = threadIdx.x & 63;
  const int wid = (blockIdx.x * 256 + threadIdx.x) >> 6;
  const int nw = (gridDim.x * 256) >> 6;
  for (int n = wid; n < n_nodes; n += nw) {
    const int s0 = row[n], s1 = row[n + 1];
    float acc = 0.f;
    int i = s0;
    for (; i + 8 <= s1; i += 8) {
      int2 b[8];
#pragma unroll
      for (int j = 0; j < 8; ++j) b[j] = bins[i + j];
      float v[8];
#pragma unroll
      for (int j = 0; j < 8; ++j)
        v[j] = __bfloat162float(xw[(size_t)b[j].x * NDOUT + lane]);
#pragma unroll
      for (int j = 0; j < 8; ++j) acc += __int_as_float(b[j].y) * v[j];
    }
    for (; i < s1; ++i) {
      const int2 b = bins[i];
      acc += __int_as_float(b.y) *
             __bfloat162float(xw[(size_t)b.x * NDOUT + lane]);
    }
    out[(size_t)n * NDOUT + lane] = fmaxf(acc, 0.f);
  }
}

// ---------------------------------------------------------------------------
// Fallback path (ws too small): atomic scatter + relu
// ---------------------------------------------------------------------------
__global__ __launch_bounds__(256) void edge_scatter_kernel(
    const __hip_bfloat16* __restrict__ xw, const float* __restrict__ ew,
    const int* __restrict__ src, const int* __restrict__ dst,
    float* __restrict__ out, int n_edges) {
  const int lane = threadIdx.x & 63;
  const int wid = (blockIdx.x * 256 + threadIdx.x) >> 6;
  const int nw = (gridDim.x * 256) >> 6;
  for (int e0 = wid * 4; e0 < n_edges; e0 += nw * 4) {
    int s[4];
    float v[4];
    bool ok[4];
#pragma unroll
    for (int j = 0; j < 4; ++j) {
      const int e = e0 + j;
      ok[j] = (e < n_edges);
      const int ee = ok[j] ? e : 0;
      s[j] = src[ee];
      v[j] = __bfloat162float(xw[(size_t)dst[ee] * NDOUT + lane]) * ew[ee];
    }
#pragma unroll
    for (int j = 0; j < 4; ++j) {
      if (ok[j]) unsafeAtomicAdd(out + (size_t)s[j] * NDOUT + lane, v[j]);
    }
  }
}

__global__ __launch_bounds__(256) void relu_kernel(float* __restrict__ out,
                                                   int n4) {
  float4* o4 = (float4*)out;
  int i = blockIdx.x * 256 + threadIdx.x;
  const int stride = gridDim.x * 256;
  for (; i < n4; i += stride) {
    float4 v = o4[i];
    v.x = fmaxf(v.x, 0.f);
    v.y = fmaxf(v.y, 0.f);
    v.z = fmaxf(v.z, 0.f);
    v.w = fmaxf(v.w, 0.f);
    o4[i] = v;
  }
}

extern "C" void kernel_launch(void* const* d_in, const int* in_sizes, int n_in,
                              void* d_out, int out_size, void* d_ws,
                              size_t ws_size, hipStream_t stream) {
  const float* x = (const float*)d_in[0];     // [N, 128]
  const float* ew = (const float*)d_in[1];    // [E]
  const float* w = (const float*)d_in[2];     // [128, 64]
  const int* esrc = (const int*)d_in[3];      // [E]
  const int* edst = (const int*)d_in[4];      // [E]
  float* out = (float*)d_out;                 // [N, 64]

  const int n_nodes = in_sizes[0] / NDIN;
  const int n_edges = in_sizes[1];

  // ws layout:
  //   xw:   N*64 bf16
  //   bins: E int2
  //   rnk:  E u16
  //   row:  (N+1) int
  //   deg:  N int
  //   bsums: 1024 int
  char* base = (char*)d_ws;
  size_t off = 0;
  __hip_bfloat16* xw = (__hip_bfloat16*)(base + off);
  off += (size_t)n_nodes * NDOUT * 2;
  off = (off + 15) & ~(size_t)15;
  int2* bins = (int2*)(base + off); off += (size_t)n_edges * 8;
  unsigned short* rnk = (unsigned short*)(base + off);
  off += (size_t)n_edges * 2;
  off = (off + 15) & ~(size_t)15;
  int* rowp = (int*)(base + off); off += (size_t)(n_nodes + 1) * 4;
  int* deg = (int*)(base + off); off += (size_t)n_nodes * 4;
  int* bsums = (int*)(base + off); off += 4096;
  const bool csr_ok = (ws_size >= off);

  // 1) xw = bf16(x @ W)
  const int gblocks = (n_nodes + BR - 1) / BR;
  gemm_xw_kernel<<<gblocks, 256, 0, stream>>>(x, w, xw, n_nodes);

  if (csr_ok) {
    // 2) CSR build without placement atomics
    hipMemsetAsync(deg, 0, (size_t)n_nodes * 4, stream);
    const int qblocks = ((n_edges + 3) / 4 + 255) / 256;
    hist_rank_kernel<<<qblocks, 256, 0, stream>>>(esrc, deg, rnk, n_edges);
    const int nb = (n_nodes + 1023) / 1024;
    scan_block_kernel<<<nb, 1024, 0, stream>>>(deg, rowp, bsums, n_nodes);
    scan_tops_kernel<<<1, 1024, 0, stream>>>(bsums, nb);
    add_off_kernel<<<(n_nodes + 255) / 256, 256, 0, stream>>>(rowp, bsums,
                                                              n_nodes, n_edges);
    place_kernel<<<qblocks, 256, 0, stream>>>(esrc, edst, ew, rowp, rnk, bins,
                                              n_edges);
    // 3) aggregate + ReLU
    aggregate_kernel<<<4096, 256, 0, stream>>>(xw, bins, rowp, out, n_nodes);
  } else {
    hipMemsetAsync(d_out, 0, (size_t)out_size * sizeof(float), stream);
    edge_scatter_kernel<<<2048, 256, 0, stream>>>(xw, ew, esrc, edst, out,
                                                  n_edges);
    relu_kernel<<<1024, 256, 0, stream>>>(out, out_size / 4);
  }
}

// Round 9
// 277.845 us; speedup vs baseline: 2.0314x; 1.1065x over previous
//
#include <hip/hip_runtime.h>
#include <hip/hip_bf16.h>

#define NDIN 128
#define NDOUT 64
#define BR 256  // rows per GEMM block
#define KC 16   // k-chunk staged in LDS

// ---------------------------------------------------------------------------
// Fused K1: role-split mega-kernel.
//   blocks [0, gblocks)          : xw = bf16(x @ W) tile  (VALU/LDS-bound)
//   blocks [gblocks, +hblocks)   : histogram + per-edge rank (atomic-bound)
// The two roles touch disjoint inputs and disjoint HW resources; fusing them
// overlaps the GEMM's compute with the hist's memory-side atomic stalls.
// ---------------------------------------------------------------------------
__global__ __launch_bounds__(256) void gemm_hist_kernel(
    const float* __restrict__ x, const float* __restrict__ w,
    __hip_bfloat16* __restrict__ xw, int n_nodes, int gblocks,
    const int* __restrict__ src, int* __restrict__ deg,
    unsigned short* __restrict__ rnk, int n_edges) {
  __shared__ float wlds[NDIN][NDOUT];  // 32 KB (gemm role only)
  __shared__ float xt[KC][BR];         // 16 KB (gemm role only)
  const int t = threadIdx.x;

  if ((int)blockIdx.x >= gblocks) {
    // ---- hist role ----
    const int hb = blockIdx.x - gblocks;
    const int tid = hb * 256 + t;
    const int base = tid * 4;
    if (base + 4 <= n_edges) {
      const int4 s4 = *(const int4*)(src + base);
      const int r0 = atomicAdd(&deg[s4.x], 1);
      const int r1 = atomicAdd(&deg[s4.y], 1);
      const int r2 = atomicAdd(&deg[s4.z], 1);
      const int r3 = atomicAdd(&deg[s4.w], 1);
      ushort4 r;
      r.x = (unsigned short)r0;
      r.y = (unsigned short)r1;
      r.z = (unsigned short)r2;
      r.w = (unsigned short)r3;
      *(ushort4*)(rnk + base) = r;
    } else if (base < n_edges) {
      for (int e = base; e < n_edges; ++e)
        rnk[e] = (unsigned short)atomicAdd(&deg[src[e]], 1);
    }
    return;
  }

  // ---- gemm role ----
  const float4* w4 = (const float4*)w;
  float4* wl4 = (float4*)(&wlds[0][0]);
#pragma unroll
  for (int i = 0; i < (NDIN * NDOUT / 4) / 256; ++i)
    wl4[t + i * 256] = w4[t + i * 256];

  const int row0 = blockIdx.x * BR;
  const int colg = t & 7;   // 8 col-groups x 8 cols
  const int rowg = t >> 3;  // 32 row-groups x 8 rows

  float acc[8][8];
#pragma unroll
  for (int i = 0; i < 8; ++i)
#pragma unroll
    for (int j = 0; j < 8; ++j) acc[i][j] = 0.f;

  for (int kc = 0; kc < NDIN; kc += KC) {
    __syncthreads();
#pragma unroll
    for (int p = 0; p < 4; ++p) {
      const int i = t + p * 256;
      const int r = i >> 2;
      const int c4 = i & 3;
      const int grow = row0 + r;
      float4 v = (grow < n_nodes)
                     ? *(const float4*)(x + (size_t)grow * NDIN + kc + c4 * 4)
                     : make_float4(0.f, 0.f, 0.f, 0.f);
      xt[c4 * 4 + 0][r] = v.x;
      xt[c4 * 4 + 1][r] = v.y;
      xt[c4 * 4 + 2][r] = v.z;
      xt[c4 * 4 + 3][r] = v.w;
    }
    __syncthreads();
#pragma unroll
    for (int k = 0; k < KC; ++k) {
      const float4 a0 = *(const float4*)(&xt[k][rowg * 8]);
      const float4 a1 = *(const float4*)(&xt[k][rowg * 8 + 4]);
      const float4 b0 = *(const float4*)(&wlds[kc + k][colg * 8]);
      const float4 b1 = *(const float4*)(&wlds[kc + k][colg * 8 + 4]);
      const float a[8] = {a0.x, a0.y, a0.z, a0.w, a1.x, a1.y, a1.z, a1.w};
      const float b[8] = {b0.x, b0.y, b0.z, b0.w, b1.x, b1.y, b1.z, b1.w};
#pragma unroll
      for (int i = 0; i < 8; ++i)
#pragma unroll
        for (int j = 0; j < 8; ++j) acc[i][j] += a[i] * b[j];
    }
  }
#pragma unroll
  for (int i = 0; i < 8; ++i) {
    const int grow = row0 + rowg * 8 + i;
    if (grow < n_nodes) {
      __hip_bfloat16 tmp[8];
#pragma unroll
      for (int j = 0; j < 8; ++j) tmp[j] = __float2bfloat16(acc[i][j]);
      *(uint4*)(xw + (size_t)grow * NDOUT + colg * 8) = *(const uint4*)tmp;
    }
  }
}

// ---------------------------------------------------------------------------
// Exclusive scan of deg -> row (3 kernels)
// ---------------------------------------------------------------------------
__global__ __launch_bounds__(1024) void scan_block_kernel(
    const int* __restrict__ deg, int* __restrict__ row,
    int* __restrict__ bsums, int n) {
  __shared__ int s[1024];
  const int t = threadIdx.x;
  const int i = blockIdx.x * 1024 + t;
  const int v = (i < n) ? deg[i] : 0;
  s[t] = v;
  __syncthreads();
#pragma unroll
  for (int off = 1; off < 1024; off <<= 1) {
    int add = (t >= off) ? s[t - off] : 0;
    __syncthreads();
    s[t] += add;
    __syncthreads();
  }
  if (i < n) row[i] = s[t] - v;  // exclusive
  if (t == 1023) bsums[blockIdx.x] = s[1023];
}

__global__ __launch_bounds__(1024) void scan_tops_kernel(int* __restrict__ bsums,
                                                         int nb) {
  __shared__ int s[1024];
  const int t = threadIdx.x;
  const int v = (t < nb) ? bsums[t] : 0;
  s[t] = v;
  __syncthreads();
#pragma unroll
  for (int off = 1; off < 1024; off <<= 1) {
    int add = (t >= off) ? s[t - off] : 0;
    __syncthreads();
    s[t] += add;
    __syncthreads();
  }
  if (t < nb) bsums[t] = s[t] - v;
}

__global__ __launch_bounds__(256) void add_off_kernel(
    int* __restrict__ row, const int* __restrict__ bsums, int n, int n_edges) {
  const int i = blockIdx.x * 256 + threadIdx.x;
  if (i < n) row[i] += bsums[i >> 10];
  if (i == 0) row[n] = n_edges;
}

// ---------------------------------------------------------------------------
// K3: placement, NO atomics: bins[row[src[e]] + rnk[e]] = {dst[e], ew[e]}
// ---------------------------------------------------------------------------
__global__ __launch_bounds__(256) void place_kernel(
    const int* __restrict__ src, const int* __restrict__ dst,
    const float* __restrict__ ew, const int* __restrict__ row,
    const unsigned short* __restrict__ rnk, int2* __restrict__ bins,
    int n_edges) {
  const int t = blockIdx.x * 256 + threadIdx.x;
  const int base = t * 4;
  if (base + 4 <= n_edges) {
    const int4 s4 = *(const int4*)(src + base);
    const int4 d4 = *(const int4*)(dst + base);
    const float4 w4 = *(const float4*)(ew + base);
    const ushort4 k4 = *(const ushort4*)(rnk + base);
    const int p0 = row[s4.x] + k4.x;
    const int p1 = row[s4.y] + k4.y;
    const int p2 = row[s4.z] + k4.z;
    const int p3 = row[s4.w] + k4.w;
    bins[p0] = make_int2(d4.x, __float_as_int(w4.x));
    bins[p1] = make_int2(d4.y, __float_as_int(w4.y));
    bins[p2] = make_int2(d4.z, __float_as_int(w4.z));
    bins[p3] = make_int2(d4.w, __float_as_int(w4.w));
  } else if (base < n_edges) {
    for (int e = base; e < n_edges; ++e)
      bins[row[src[e]] + rnk[e]] = make_int2(dst[e], __float_as_int(ew[e]));
  }
}

// ---------------------------------------------------------------------------
// K4: aggregate. One wave per node, lane = column. bins reads sequential
// per-node; xw row gathers bf16 (128 B/edge), 8 in flight. ReLU fused.
// ---------------------------------------------------------------------------
__global__ __launch_bounds__(256) void aggregate_kernel(
    const __hip_bfloat16* __restrict__ xw, const int2* __restrict__ bins,
    const int* __restrict__ row, float* __restrict__ out, int n_nodes) {
  const int lane = threadIdx.x & 63;
  const int wid = (blockIdx.x * 256 + threadIdx.x) >> 6;
  const int nw = (gridDim.x * 256) >> 6;
  for (int n = wid; n < n_nodes; n += nw) {
    const int s0 = row[n], s1 = row[n + 1];
    float acc = 0.f;
    int i = s0;
    for (; i + 8 <= s1; i += 8) {
      int2 b[8];
#pragma unroll
      for (int j = 0; j < 8; ++j) b[j] = bins[i + j];
      float v[8];
#pragma unroll
      for (int j = 0; j < 8; ++j)
        v[j] = __bfloat162float(xw[(size_t)b[j].x * NDOUT + lane]);
#pragma unroll
      for (int j = 0; j < 8; ++j) acc += __int_as_float(b[j].y) * v[j];
    }
    for (; i < s1; ++i) {
      const int2 b = bins[i];
      acc += __int_as_float(b.y) *
             __bfloat162float(xw[(size_t)b.x * NDOUT + lane]);
    }
    out[(size_t)n * NDOUT + lane] = fmaxf(acc, 0.f);
  }
}

// ---------------------------------------------------------------------------
// Fallback path (ws too small): plain gemm + atomic scatter + relu
// ---------------------------------------------------------------------------
__global__ __launch_bounds__(256) void edge_scatter_kernel(
    const __hip_bfloat16* __restrict__ xw, const float* __restrict__ ew,
    const int* __restrict__ src, const int* __restrict__ dst,
    float* __restrict__ out, int n_edges) {
  const int lane = threadIdx.x & 63;
  const int wid = (blockIdx.x * 256 + threadIdx.x) >> 6;
  const int nw = (gridDim.x * 256) >> 6;
  for (int e0 = wid * 4; e0 < n_edges; e0 += nw * 4) {
    int s[4];
    float v[4];
    bool ok[4];
#pragma unroll
    for (int j = 0; j < 4; ++j) {
      const int e = e0 + j;
      ok[j] = (e < n_edges);
      const int ee = ok[j] ? e : 0;
      s[j] = src[ee];
      v[j] = __bfloat162float(xw[(size_t)dst[ee] * NDOUT + lane]) * ew[ee];
    }
#pragma unroll
    for (int j = 0; j < 4; ++j) {
      if (ok[j]) unsafeAtomicAdd(out + (size_t)s[j] * NDOUT + lane, v[j]);
    }
  }
}

__global__ __launch_bounds__(256) void relu_kernel(float* __restrict__ out,
                                                   int n4) {
  float4* o4 = (float4*)out;
  int i = blockIdx.x * 256 + threadIdx.x;
  const int stride = gridDim.x * 256;
  for (; i < n4; i += stride) {
    float4 v = o4[i];
    v.x = fmaxf(v.x, 0.f);
    v.y = fmaxf(v.y, 0.f);
    v.z = fmaxf(v.z, 0.f);
    v.w = fmaxf(v.w, 0.f);
    o4[i] = v;
  }
}

extern "C" void kernel_launch(void* const* d_in, const int* in_sizes, int n_in,
                              void* d_out, int out_size, void* d_ws,
                              size_t ws_size, hipStream_t stream) {
  const float* x = (const float*)d_in[0];     // [N, 128]
  const float* ew = (const float*)d_in[1];    // [E]
  const float* w = (const float*)d_in[2];     // [128, 64]
  const int* esrc = (const int*)d_in[3];      // [E]
  const int* edst = (const int*)d_in[4];      // [E]
  float* out = (float*)d_out;                 // [N, 64]

  const int n_nodes = in_sizes[0] / NDIN;
  const int n_edges = in_sizes[1];

  // ws layout:
  //   xw:   N*64 bf16
  //   bins: E int2
  //   rnk:  E u16
  //   row:  (N+1) int
  //   deg:  N int
  //   bsums: 1024 int
  char* base = (char*)d_ws;
  size_t off = 0;
  __hip_bfloat16* xw = (__hip_bfloat16*)(base + off);
  off += (size_t)n_nodes * NDOUT * 2;
  off = (off + 15) & ~(size_t)15;
  int2* bins = (int2*)(base + off); off += (size_t)n_edges * 8;
  unsigned short* rnk = (unsigned short*)(base + off);
  off += (size_t)n_edges * 2;
  off = (off + 15) & ~(size_t)15;
  int* rowp = (int*)(base + off); off += (size_t)(n_nodes + 1) * 4;
  int* deg = (int*)(base + off); off += (size_t)n_nodes * 4;
  int* bsums = (int*)(base + off); off += 4096;
  const bool csr_ok = (ws_size >= off);

  const int gblocks = (n_nodes + BR - 1) / BR;

  if (csr_ok) {
    // 1) deg = 0 (must precede fused kernel's hist role)
    hipMemsetAsync(deg, 0, (size_t)n_nodes * 4, stream);
    // 2) fused GEMM + hist (overlap compute-bound with atomic-bound)
    const int hblocks = ((n_edges + 3) / 4 + 255) / 256;
    gemm_hist_kernel<<<gblocks + hblocks, 256, 0, stream>>>(
        x, w, xw, n_nodes, gblocks, esrc, deg, rnk, n_edges);
    // 3) scan deg -> row
    const int nb = (n_nodes + 1023) / 1024;
    scan_block_kernel<<<nb, 1024, 0, stream>>>(deg, rowp, bsums, n_nodes);
    scan_tops_kernel<<<1, 1024, 0, stream>>>(bsums, nb);
    add_off_kernel<<<(n_nodes + 255) / 256, 256, 0, stream>>>(rowp, bsums,
                                                              n_nodes, n_edges);
    // 4) placement (no atomics)
    place_kernel<<<hblocks, 256, 0, stream>>>(esrc, edst, ew, rowp, rnk, bins,
                                              n_edges);
    // 5) aggregate + ReLU
    aggregate_kernel<<<4096, 256, 0, stream>>>(xw, bins, rowp, out, n_nodes);
  } else {
    gemm_hist_kernel<<<gblocks, 256, 0, stream>>>(
        x, w, xw, n_nodes, gblocks, esrc, (int*)d_out, (unsigned short*)d_out,
        0);  // gemm-only (hist range empty since grid == gblocks)
    hipMemsetAsync(d_out, 0, (size_t)out_size * sizeof(float), stream);
    edge_scatter_kernel<<<2048, 256, 0, stream>>>(xw, ew, esrc, edst, out,
                                                  n_edges);
    relu_kernel<<<1024, 256, 0, stream>>>(out, out_size / 4);
  }
}